// Round 1
// baseline (7734.671 us; speedup 1.0000x reference)
//
#include <hip/hip_runtime.h>
#include <cstdint>

#define DEV __device__ __forceinline__

// Order-preserving float <-> uint encoding:
// enc is strictly monotone: a < b (float) <=> enc(a) < enc(b) (uint)
DEV unsigned encf(float f) {
    unsigned u = __float_as_uint(f);
    return (u & 0x80000000u) ? ~u : (u | 0x80000000u);
}
DEV float decf(unsigned e) {
    unsigned u = (e & 0x80000000u) ? (e ^ 0x80000000u) : ~e;
    return __uint_as_float(u);
}

// Row layout per label: [min x16 | max x16 | sum->mean x16 | s]  (49 floats)
// Both regions have row length 49, and region 2 starts at L1*49 (multiple of 49),
// so col = idx % 49 is valid globally over the concatenated output.

__global__ __launch_bounds__(256) void init_out_kernel(unsigned* __restrict__ out, int total) {
    int stride = gridDim.x * blockDim.x;
    for (int idx = blockIdx.x * blockDim.x + threadIdx.x; idx < total; idx += stride) {
        int col = idx % 49;
        // min slots -> 0xFFFFFFFF (encoded +max), max slots -> 0 (encoded -max),
        // sum slots -> 0.0f (bits 0), s col -> overwritten by finalize anyway.
        out[idx] = (col < 16) ? 0xFFFFFFFFu : 0u;
    }
}

__global__ __launch_bounds__(256) void main_pass_kernel(
    const float4* __restrict__ x4,
    const int* __restrict__ m1, const int* __restrict__ m2,
    unsigned* __restrict__ o1, unsigned* __restrict__ o2,
    int nq /* = Npix*4 */) {
    int stride = gridDim.x * blockDim.x;
    for (int t = blockIdx.x * blockDim.x + threadIdx.x; t < nq; t += stride) {
        float4 v = x4[t];                // coalesced 16B/lane
        int p = t >> 2;
        int q = (t & 3) << 2;            // channel offset 0,4,8,12
        int l1 = m1[p];
        int l2 = m2[p];
        unsigned e0 = encf(v.x), e1 = encf(v.y), e2 = encf(v.z), e3 = encf(v.w);

        {
            unsigned* r = o1 + (size_t)l1 * 49 + q;
            atomicMin(r + 0,  e0); atomicMin(r + 1,  e1);
            atomicMin(r + 2,  e2); atomicMin(r + 3,  e3);
            atomicMax(r + 16, e0); atomicMax(r + 17, e1);
            atomicMax(r + 18, e2); atomicMax(r + 19, e3);
            float* f = (float*)(r + 32);
            unsafeAtomicAdd(f + 0, v.x); unsafeAtomicAdd(f + 1, v.y);
            unsafeAtomicAdd(f + 2, v.z); unsafeAtomicAdd(f + 3, v.w);
        }
        {
            unsigned* r = o2 + (size_t)l2 * 49 + q;
            atomicMin(r + 0,  e0); atomicMin(r + 1,  e1);
            atomicMin(r + 2,  e2); atomicMin(r + 3,  e3);
            atomicMax(r + 16, e0); atomicMax(r + 17, e1);
            atomicMax(r + 18, e2); atomicMax(r + 19, e3);
            float* f = (float*)(r + 32);
            unsafeAtomicAdd(f + 0, v.x); unsafeAtomicAdd(f + 1, v.y);
            unsafeAtomicAdd(f + 2, v.z); unsafeAtomicAdd(f + 3, v.w);
        }
    }
}

__global__ __launch_bounds__(256) void finalize_kernel(
    unsigned* __restrict__ out,
    const int* __restrict__ s1, const int* __restrict__ s2,
    int L1, int L2) {
    int total = (L1 + L2) * 49;
    int boundary = L1 * 49;
    int stride = gridDim.x * blockDim.x;
    for (int idx = blockIdx.x * blockDim.x + threadIdx.x; idx < total; idx += stride) {
        int col = idx % 49;
        int row = idx / 49;
        int size = (idx < boundary) ? s1[row] : s2[row - L1];
        unsigned e = out[idx];
        float r;
        if (col < 32) {
            r = decf(e);                              // decode min/max in place
        } else if (col < 48) {
            r = __uint_as_float(e) / (float)size;     // sum -> mean
        } else {
            r = expf(-(float)size) - 0.5f;            // s column
        }
        ((float*)out)[idx] = r;
    }
}

extern "C" void kernel_launch(void* const* d_in, const int* in_sizes, int n_in,
                              void* d_out, int out_size, void* d_ws, size_t ws_size,
                              hipStream_t stream) {
    const float* x  = (const float*)d_in[0];
    const int*   m1 = (const int*)d_in[1];
    const int*   m2 = (const int*)d_in[2];
    const int*   s1 = (const int*)d_in[3];
    const int*   s2 = (const int*)d_in[4];
    int Npix = in_sizes[1];           // 4,000,000
    int L1   = in_sizes[3];           // 50,000
    int L2   = in_sizes[4];           // 30,000

    unsigned* o1 = (unsigned*)d_out;
    unsigned* o2 = o1 + (size_t)L1 * 49;
    int total = (L1 + L2) * 49;

    int initBlocks = (total + 255) / 256;
    init_out_kernel<<<initBlocks, 256, 0, stream>>>((unsigned*)d_out, total);

    int nq = Npix * 4;
    main_pass_kernel<<<2048, 256, 0, stream>>>(
        (const float4*)x, m1, m2, o1, o2, nq);

    finalize_kernel<<<initBlocks, 256, 0, stream>>>((unsigned*)d_out, s1, s2, L1, L2);
}

// Round 2
// 1265.435 us; speedup vs baseline: 6.1123x; 6.1123x over previous
//
#include <hip/hip_runtime.h>
#include <cstdint>
#include <math.h>

#define DEV __device__ __forceinline__

// ============================ CSR sort-gather path ============================
//
// ws layout (u32):  cur1[L1] | cur2[L2] | perm1[N] | perm2[N]
// Phase 1: exclusive-scan sizes -> cur (per mask).
// Phase 2: place: pos = atomicAdd(cur[label]); perm[pos] = pixel.  (8M atomics)
//          After phase 2, cur[l] == inclusive scan, so start = cur[l] - size[l].
// Phase 3: one wave per label: gather + in-register reduce, write 49-col row.

__global__ __launch_bounds__(1024) void scan_kernel(const int* __restrict__ s,
                                                    unsigned* __restrict__ cur, int L) {
    __shared__ unsigned wsum[16];
    __shared__ unsigned carry_s;
    int lane = threadIdx.x & 63;
    int wid  = threadIdx.x >> 6;
    if (threadIdx.x == 0) carry_s = 0;
    __syncthreads();
    for (int base = 0; base < L; base += 1024) {
        int i = base + (int)threadIdx.x;
        unsigned v = (i < L) ? (unsigned)s[i] : 0u;
        unsigned incl = v;
        #pragma unroll
        for (int off = 1; off < 64; off <<= 1) {
            unsigned t = __shfl_up(incl, off, 64);
            if (lane >= off) incl += t;
        }
        if (lane == 63) wsum[wid] = incl;
        __syncthreads();
        if (wid == 0) {
            unsigned ws = (lane < 16) ? wsum[lane] : 0u;
            #pragma unroll
            for (int off = 1; off < 16; off <<= 1) {
                unsigned t = __shfl_up(ws, off, 64);
                if (lane >= off) ws += t;
            }
            if (lane < 16) wsum[lane] = ws;   // inclusive over waves
        }
        __syncthreads();
        unsigned wave_excl = (wid == 0) ? 0u : wsum[wid - 1];
        unsigned excl = carry_s + wave_excl + incl - v;
        if (i < L) cur[i] = excl;
        unsigned total = wsum[15];
        __syncthreads();                       // all reads of carry_s/wsum done
        if (threadIdx.x == 0) carry_s += total;
        __syncthreads();                       // update visible before next iter
    }
}

__global__ __launch_bounds__(256) void place_kernel(
    const int* __restrict__ m1, const int* __restrict__ m2,
    unsigned* __restrict__ cur1, unsigned* __restrict__ cur2,
    unsigned* __restrict__ perm1, unsigned* __restrict__ perm2, int n) {
    int stride = gridDim.x * blockDim.x;
    int total = 2 * n;
    for (int t = blockIdx.x * blockDim.x + threadIdx.x; t < total; t += stride) {
        if (t < n) {
            int l = m1[t];
            unsigned pos = atomicAdd(&cur1[l], 1u);
            perm1[pos] = (unsigned)t;
        } else {
            int p = t - n;
            int l = m2[p];
            unsigned pos = atomicAdd(&cur2[l], 1u);
            perm2[pos] = (unsigned)p;
        }
    }
}

__global__ __launch_bounds__(256) void gather_kernel(
    const float* __restrict__ x,
    const unsigned* __restrict__ perm1, const unsigned* __restrict__ perm2,
    const unsigned* __restrict__ cur1, const unsigned* __restrict__ cur2,
    const int* __restrict__ s1, const int* __restrict__ s2,
    float* __restrict__ out, int L1, int L2) {
    int wave = blockIdx.x * (blockDim.x >> 6) + ((int)threadIdx.x >> 6);
    int lane = (int)threadIdx.x & 63;
    int c = lane & 15, slice = lane >> 4;

    const unsigned* perm;
    int size, start;
    float* row;
    if (wave < L1) {
        size = s1[wave]; start = (int)cur1[wave] - size; perm = perm1;
        row = out + (size_t)wave * 49;
    } else if (wave < L1 + L2) {
        int l = wave - L1;
        size = s2[l]; start = (int)cur2[l] - size; perm = perm2;
        row = out + (size_t)(L1 + l) * 49;
    } else return;

    // Two independent pixel streams per lane for MLP (stride 8 each).
    float mn0 = INFINITY, mx0 = -INFINITY, sm0 = 0.f;
    float mn1 = INFINITY, mx1 = -INFINITY, sm1 = 0.f;
    int j0 = slice, j1 = slice + 4;
    unsigned p0 = (j0 < size) ? perm[start + j0] : 0u;
    unsigned p1 = (j1 < size) ? perm[start + j1] : 0u;
    while (j0 < size) {
        int n0 = j0 + 8, n1 = j1 + 8;
        unsigned q0 = (n0 < size) ? perm[start + n0] : 0u;
        unsigned q1 = (n1 < size) ? perm[start + n1] : 0u;
        float v0 = x[(size_t)p0 * 16 + c];
        mn0 = fminf(mn0, v0); mx0 = fmaxf(mx0, v0); sm0 += v0;
        if (j1 < size) {
            float v1 = x[(size_t)p1 * 16 + c];
            mn1 = fminf(mn1, v1); mx1 = fmaxf(mx1, v1); sm1 += v1;
        }
        j0 = n0; j1 = n1; p0 = q0; p1 = q1;
    }
    float mn = fminf(mn0, mn1), mx = fmaxf(mx0, mx1), sm = sm0 + sm1;

    // Reduce across the 4 slices (lanes c, c+16, c+32, c+48).
    #pragma unroll
    for (int off = 16; off < 64; off <<= 1) {
        mn = fminf(mn, __shfl_xor(mn, off, 64));
        mx = fmaxf(mx, __shfl_xor(mx, off, 64));
        sm += __shfl_xor(sm, off, 64);
    }
    if (slice == 0) {
        row[c] = mn;
        row[16 + c] = mx;
        row[32 + c] = sm / (float)size;
        if (c == 0) row[48] = expf(-(float)size) - 0.5f;
    }
}

// ============================ fallback (R0 atomic path) ============================

DEV unsigned encf(float f) {
    unsigned u = __float_as_uint(f);
    return (u & 0x80000000u) ? ~u : (u | 0x80000000u);
}
DEV float decf(unsigned e) {
    unsigned u = (e & 0x80000000u) ? (e ^ 0x80000000u) : ~u;
    return __uint_as_float(u);
}

__global__ __launch_bounds__(256) void init_out_kernel(unsigned* __restrict__ out, int total) {
    int stride = gridDim.x * blockDim.x;
    for (int idx = blockIdx.x * blockDim.x + threadIdx.x; idx < total; idx += stride) {
        int col = idx % 49;
        out[idx] = (col < 16) ? 0xFFFFFFFFu : 0u;
    }
}

__global__ __launch_bounds__(256) void main_pass_kernel(
    const float4* __restrict__ x4,
    const int* __restrict__ m1, const int* __restrict__ m2,
    unsigned* __restrict__ o1, unsigned* __restrict__ o2, int nq) {
    int stride = gridDim.x * blockDim.x;
    for (int t = blockIdx.x * blockDim.x + threadIdx.x; t < nq; t += stride) {
        float4 v = x4[t];
        int p = t >> 2;
        int q = (t & 3) << 2;
        int l1 = m1[p], l2 = m2[p];
        unsigned e0 = encf(v.x), e1 = encf(v.y), e2 = encf(v.z), e3 = encf(v.w);
        {
            unsigned* r = o1 + (size_t)l1 * 49 + q;
            atomicMin(r + 0, e0);  atomicMin(r + 1, e1);
            atomicMin(r + 2, e2);  atomicMin(r + 3, e3);
            atomicMax(r + 16, e0); atomicMax(r + 17, e1);
            atomicMax(r + 18, e2); atomicMax(r + 19, e3);
            float* f = (float*)(r + 32);
            unsafeAtomicAdd(f + 0, v.x); unsafeAtomicAdd(f + 1, v.y);
            unsafeAtomicAdd(f + 2, v.z); unsafeAtomicAdd(f + 3, v.w);
        }
        {
            unsigned* r = o2 + (size_t)l2 * 49 + q;
            atomicMin(r + 0, e0);  atomicMin(r + 1, e1);
            atomicMin(r + 2, e2);  atomicMin(r + 3, e3);
            atomicMax(r + 16, e0); atomicMax(r + 17, e1);
            atomicMax(r + 18, e2); atomicMax(r + 19, e3);
            float* f = (float*)(r + 32);
            unsafeAtomicAdd(f + 0, v.x); unsafeAtomicAdd(f + 1, v.y);
            unsafeAtomicAdd(f + 2, v.z); unsafeAtomicAdd(f + 3, v.w);
        }
    }
}

__global__ __launch_bounds__(256) void finalize_kernel(
    unsigned* __restrict__ out,
    const int* __restrict__ s1, const int* __restrict__ s2, int L1, int L2) {
    int total = (L1 + L2) * 49;
    int boundary = L1 * 49;
    int stride = gridDim.x * blockDim.x;
    for (int idx = blockIdx.x * blockDim.x + threadIdx.x; idx < total; idx += stride) {
        int col = idx % 49;
        int row = idx / 49;
        int size = (idx < boundary) ? s1[row] : s2[row - L1];
        unsigned e = out[idx];
        float r;
        if (col < 32)      r = decf(e);
        else if (col < 48) r = __uint_as_float(e) / (float)size;
        else               r = expf(-(float)size) - 0.5f;
        ((float*)out)[idx] = r;
    }
}

// ============================ launch ============================

extern "C" void kernel_launch(void* const* d_in, const int* in_sizes, int n_in,
                              void* d_out, int out_size, void* d_ws, size_t ws_size,
                              hipStream_t stream) {
    const float* x  = (const float*)d_in[0];
    const int*   m1 = (const int*)d_in[1];
    const int*   m2 = (const int*)d_in[2];
    const int*   s1 = (const int*)d_in[3];
    const int*   s2 = (const int*)d_in[4];
    int Npix = in_sizes[1];
    int L1   = in_sizes[3];
    int L2   = in_sizes[4];

    size_t need = ((size_t)L1 + (size_t)L2 + 2ull * (size_t)Npix) * 4ull;
    if (ws_size >= need) {
        unsigned* cur1  = (unsigned*)d_ws;
        unsigned* cur2  = cur1 + L1;
        unsigned* perm1 = cur2 + L2;
        unsigned* perm2 = perm1 + Npix;

        scan_kernel<<<1, 1024, 0, stream>>>(s1, cur1, L1);
        scan_kernel<<<1, 1024, 0, stream>>>(s2, cur2, L2);
        place_kernel<<<2048, 256, 0, stream>>>(m1, m2, cur1, cur2, perm1, perm2, Npix);
        int waves = L1 + L2;
        int blocks = (waves + 3) / 4;   // 4 waves (256 thr) per block
        gather_kernel<<<blocks, 256, 0, stream>>>(
            x, perm1, perm2, cur1, cur2, s1, s2, (float*)d_out, L1, L2);
    } else {
        // fallback: R0 atomic path (accumulate in-place in d_out)
        unsigned* o1 = (unsigned*)d_out;
        unsigned* o2 = o1 + (size_t)L1 * 49;
        int total = (L1 + L2) * 49;
        int initBlocks = (total + 255) / 256;
        init_out_kernel<<<initBlocks, 256, 0, stream>>>((unsigned*)d_out, total);
        main_pass_kernel<<<2048, 256, 0, stream>>>(
            (const float4*)x, m1, m2, o1, o2, Npix * 4);
        finalize_kernel<<<initBlocks, 256, 0, stream>>>((unsigned*)d_out, s1, s2, L1, L2);
    }
}